// Round 22
// baseline (229.102 us; speedup 1.0000x reference)
//
#include <hip/hip_runtime.h>

#define NROWS 1000000
#define NB    3907
#define NT    62500
#define TPB   4
#define NBATCH (NT / TPB)
#define MLP_BLOCKS 768
#define MLP_THREADS 512

typedef __bf16 bf16x8 __attribute__((ext_vector_type(8)));
typedef float  f32x4  __attribute__((ext_vector_type(4)));

__device__ __forceinline__ unsigned cvt_pk_bf16(float lo, float hi) {
  unsigned r;
  asm("v_cvt_pk_bf16_f32 %0, %1, %2" : "=v"(r) : "v"(lo), "v"(hi));
  return r;
}

// ---------------------------------------------------------------------------
// Kernel 1: per-256-row-block nonzero counts.
// ---------------------------------------------------------------------------
__global__ __launch_bounds__(256) void count_kernel(
    const int* __restrict__ mask, int* __restrict__ bsum) {
  int tid = threadIdx.x;
  int row = blockIdx.x * 256 + tid;
  int cnt = 0;
  if (row < NROWS) {
    const int4* mp = (const int4*)(mask + (long)row * 8);
    int4 a = mp[0], b = mp[1];
    cnt = (a.x != 0) + (a.y != 0) + (a.z != 0) + (a.w != 0) +
          (b.x != 0) + (b.y != 0) + (b.z != 0) + (b.w != 0);
  }
#pragma unroll
  for (int off = 1; off < 64; off <<= 1) cnt += __shfl_xor(cnt, off);
  __shared__ int ws[4];
  if ((tid & 63) == 0) ws[tid >> 6] = cnt;
  __syncthreads();
  if (tid == 0) bsum[blockIdx.x] = ws[0] + ws[1] + ws[2] + ws[3];
}

// ---------------------------------------------------------------------------
// Kernel 2: exclusive scan of block sums.
// ---------------------------------------------------------------------------
__global__ __launch_bounds__(1024) void scan_kernel(
    const int* __restrict__ bsum, int* __restrict__ boff) {
  __shared__ int lds[1024];
  int t = threadIdx.x;
  int i0 = t * 4;
  int c0 = (i0 + 0 < NB) ? bsum[i0 + 0] : 0;
  int c1 = (i0 + 1 < NB) ? bsum[i0 + 1] : 0;
  int c2 = (i0 + 2 < NB) ? bsum[i0 + 2] : 0;
  int c3 = (i0 + 3 < NB) ? bsum[i0 + 3] : 0;
  int s = c0 + c1 + c2 + c3;
  lds[t] = s;
  __syncthreads();
  for (int off = 1; off < 1024; off <<= 1) {
    int v = lds[t];
    int add = (t >= off) ? lds[t - off] : 0;
    __syncthreads();
    lds[t] = v + add;
    __syncthreads();
  }
  int excl = lds[t] - s;
  if (i0 + 0 < NB) boff[i0 + 0] = excl;
  excl += c0;
  if (i0 + 1 < NB) boff[i0 + 1] = excl;
  excl += c1;
  if (i0 + 2 < NB) boff[i0 + 2] = excl;
  excl += c2;
  if (i0 + 3 < NB) boff[i0 + 3] = excl;
}

// ---------------------------------------------------------------------------
// Kernel 3: per-row info = (scatter_pos << 8) | mask_bits.
// ---------------------------------------------------------------------------
__global__ __launch_bounds__(256) void expand_kernel(
    const int* __restrict__ mask, const int* __restrict__ boff,
    int* __restrict__ rowinfo) {
  int tid = threadIdx.x;
  int row = blockIdx.x * 256 + tid;
  bool valid = row < NROWS;
  unsigned mb = 0;
  int cnt = 0;
  if (valid) {
    const int4* mp = (const int4*)(mask + (long)row * 8);
    int4 a = mp[0], b = mp[1];
    mb = (unsigned)((a.x != 0) | ((a.y != 0) << 1) | ((a.z != 0) << 2) |
                    ((a.w != 0) << 3) | ((b.x != 0) << 4) | ((b.y != 0) << 5) |
                    ((b.z != 0) << 6) | ((b.w != 0) << 7));
    cnt = __popc(mb);
  }
  int incl = cnt;
#pragma unroll
  for (int off = 1; off < 64; off <<= 1) {
    int v = __shfl_up(incl, off);
    if ((tid & 63) >= off) incl += v;
  }
  __shared__ int wsum[4];
  if ((tid & 63) == 63) wsum[tid >> 6] = incl;
  __syncthreads();
  int w = tid >> 6;
  int wo = 0;
  if (w > 0) wo += wsum[0];
  if (w > 1) wo += wsum[1];
  if (w > 2) wo += wsum[2];
  int pos = boff[blockIdx.x] + wo + (incl - cnt);
  if (valid) rowinfo[row] = (pos << 8) | (int)mb;
}

// ---------------------------------------------------------------------------
// Kernel 4 (DIAGNOSTIC TEMPLATE):
//  M0: R19 exactly (real out).  M1: no LDS in loop (Aw:=xf, C:=b1C).
//  M2: M1 + no cvt (bitcast B).  M3: M2 + 4 independent O chains (depth 8->4).
//  M1-3 keep all MFMAs live via keep-sum -> dbg.
// ---------------------------------------------------------------------------
template <int MODE>
__global__ __launch_bounds__(MLP_THREADS, 4) void mlp_t(
    const float* __restrict__ x, const float* __restrict__ w0,
    const float* __restrict__ b0, const float* __restrict__ w1,
    const float* __restrict__ b1, const int* __restrict__ rowinfo,
    float* __restrict__ out, float* __restrict__ dbg) {
  __shared__ __bf16 sA[32 * 64 * 8];
  __shared__ float sB0[512];

  int tid = threadIdx.x;
#pragma unroll
  for (int i = 0; i < 4; ++i) {
    int fi = i * MLP_THREADS + tid;
    int frag = fi >> 6;
    int lane = fi & 63;
    int d = frag >> 2, qb = frag & 3;
    int q = qb * 16 + (lane & 15);
    int kb = (lane >> 4) * 8;
    bf16x8 v;
#pragma unroll
    for (int j = 0; j < 8; ++j)
      v[j] = (__bf16)w0[d * 2048 + (kb + j) * 64 + q];
    *(bf16x8*)&sA[fi * 8] = v;
  }
  if (tid < 128) *(float4*)&sB0[tid * 4] = *(const float4*)&b0[tid * 4];
  __syncthreads();

  int l = tid & 63;
  int n = l & 15;
  int g = l >> 4;

  bf16x8 w1A, w1B;
  bool ownrow = (n < 8);
#pragma unroll
  for (int j = 0; j < 8; ++j) {
    int off = (j >> 2) * 16 + g * 4 + (j & 3);
    w1A[j] = ownrow ? (__bf16)w1[n * 64 + off]      : (__bf16)0.f;
    w1B[j] = ownrow ? (__bf16)w1[n * 64 + 32 + off] : (__bf16)0.f;
  }
  int4 w1Ai = *(int4*)&w1A;
  int4 w1Bi = *(int4*)&w1B;
  f32x4 b1C;
#pragma unroll
  for (int r = 0; r < 4; ++r) b1C[r] = b1[(g * 4 + r) & 7];

  int w = tid >> 6;
  int wv = blockIdx.x * 8 + w;
  const int W = MLP_BLOCKS * 8;
  float keep = 0.f;

  for (int b = wv; b < NBATCH; b += W) {
    int t0 = b * TPB;

    bf16x8 xf0, xf1, xf2, xf3;
    {
      const float* xp;
      float4 a, c;
      uint4 ui;
#define LOADX(T, DST)                                              \
      xp = x + (long)((t0 + T) * 16 + n) * 32 + g * 8;             \
      a = *(const float4*)xp; c = *(const float4*)(xp + 4);        \
      ui.x = cvt_pk_bf16(a.x, a.y); ui.y = cvt_pk_bf16(a.z, a.w); \
      ui.z = cvt_pk_bf16(c.x, c.y); ui.w = cvt_pk_bf16(c.z, c.w); \
      DST = *(bf16x8*)&ui;
      LOADX(0, xf0) LOADX(1, xf1) LOADX(2, xf2) LOADX(3, xf3)
#undef LOADX
    }

    f32x4 O0 = b1C, O1 = b1C, O2 = b1C, O3 = b1C;
    f32x4 P0 = b1C, P1 = b1C, P2 = b1C, P3 = b1C;  // MODE 3 extra chains

#pragma unroll 1
    for (int cp = 0; cp < 8; ++cp) {
      bool own = (n == cp);
      int4 z4 = {0, 0, 0, 0};
      int4 A2ai = own ? w1Ai : z4;
      int4 A2bi = own ? w1Bi : z4;
      bf16x8 A2a = *(bf16x8*)&A2ai;
      bf16x8 A2b = *(bf16x8*)&A2bi;
      int fb2 = cp * 4;
      bf16x8 Aw0, Aw1, Aw2, Aw3;
      f32x4 C0, C1, C2, C3;
      if constexpr (MODE == 0) {
        Aw0 = *(const bf16x8*)&sA[(fb2 + 0) * 512 + l * 8];
        Aw1 = *(const bf16x8*)&sA[(fb2 + 1) * 512 + l * 8];
        Aw2 = *(const bf16x8*)&sA[(fb2 + 2) * 512 + l * 8];
        Aw3 = *(const bf16x8*)&sA[(fb2 + 3) * 512 + l * 8];
        C0 = *(const f32x4*)&sB0[(fb2 + 0) * 16 + g * 4];
        C1 = *(const f32x4*)&sB0[(fb2 + 1) * 16 + g * 4];
        C2 = *(const f32x4*)&sB0[(fb2 + 2) * 16 + g * 4];
        C3 = *(const f32x4*)&sB0[(fb2 + 3) * 16 + g * 4];
      } else {
        Aw0 = xf0; Aw1 = xf1; Aw2 = xf2; Aw3 = xf3;  // register operands
        C0 = b1C; C1 = b1C; C2 = b1C; C3 = b1C;
      }

#define MKB(BU, Dp, Dq)                                                       \
      if constexpr (MODE >= 2) {                                              \
        BU.x = __float_as_uint(Dp[0]); BU.y = __float_as_uint(Dp[2]);         \
        BU.z = __float_as_uint(Dq[0]); BU.w = __float_as_uint(Dq[2]);         \
      } else {                                                                \
        BU.x = cvt_pk_bf16(fmaxf(Dp[0], 0.f), fmaxf(Dp[1], 0.f));             \
        BU.y = cvt_pk_bf16(fmaxf(Dp[2], 0.f), fmaxf(Dp[3], 0.f));             \
        BU.z = cvt_pk_bf16(fmaxf(Dq[0], 0.f), fmaxf(Dq[1], 0.f));             \
        BU.w = cvt_pk_bf16(fmaxf(Dq[2], 0.f), fmaxf(Dq[3], 0.f));             \
      }

#define TILE2(XFa, OA, PA, XFb, OB, PB) {                                     \
      f32x4 Da0 = __builtin_amdgcn_mfma_f32_16x16x32_bf16(Aw0, XFa, C0,0,0,0);\
      f32x4 Db0 = __builtin_amdgcn_mfma_f32_16x16x32_bf16(Aw0, XFb, C0,0,0,0);\
      f32x4 Da1 = __builtin_amdgcn_mfma_f32_16x16x32_bf16(Aw1, XFa, C1,0,0,0);\
      f32x4 Db1 = __builtin_amdgcn_mfma_f32_16x16x32_bf16(Aw1, XFb, C1,0,0,0);\
      uint4 ua, ub;                                                           \
      MKB(ua, Da0, Da1)                                                       \
      MKB(ub, Db0, Db1)                                                       \
      bf16x8 B2a = *(bf16x8*)&ua;                                             \
      bf16x8 B2b = *(bf16x8*)&ub;                                             \
      OA = __builtin_amdgcn_mfma_f32_16x16x32_bf16(A2a, B2a, OA, 0, 0, 0);    \
      OB = __builtin_amdgcn_mfma_f32_16x16x32_bf16(A2a, B2b, OB, 0, 0, 0);    \
      f32x4 Da2 = __builtin_amdgcn_mfma_f32_16x16x32_bf16(Aw2, XFa, C2,0,0,0);\
      f32x4 Db2 = __builtin_amdgcn_mfma_f32_16x16x32_bf16(Aw2, XFb, C2,0,0,0);\
      f32x4 Da3 = __builtin_amdgcn_mfma_f32_16x16x32_bf16(Aw3, XFa, C3,0,0,0);\
      f32x4 Db3 = __builtin_amdgcn_mfma_f32_16x16x32_bf16(Aw3, XFb, C3,0,0,0);\
      MKB(ua, Da2, Da3)                                                       \
      MKB(ub, Db2, Db3)                                                       \
      bf16x8 B3a = *(bf16x8*)&ua;                                             \
      bf16x8 B3b = *(bf16x8*)&ub;                                             \
      if constexpr (MODE == 3) {                                              \
        PA = __builtin_amdgcn_mfma_f32_16x16x32_bf16(A2b, B3a, PA, 0, 0, 0);  \
        PB = __builtin_amdgcn_mfma_f32_16x16x32_bf16(A2b, B3b, PB, 0, 0, 0);  \
      } else {                                                                \
        OA = __builtin_amdgcn_mfma_f32_16x16x32_bf16(A2b, B3a, OA, 0, 0, 0);  \
        OB = __builtin_amdgcn_mfma_f32_16x16x32_bf16(A2b, B3b, OB, 0, 0, 0);  \
      }                                                                       }
      TILE2(xf0, O0, P0, xf1, O1, P1)
      TILE2(xf2, O2, P2, xf3, O3, P3)
#undef TILE2
#undef MKB
    }

    if constexpr (MODE == 0) {
      if (g < 2) {
#define EPI(T, OD) {                                                     \
        int row = (t0 + T) * 16 + n;                                     \
        int info = rowinfo[row];                                         \
        unsigned mb = (unsigned)info & 255u;                             \
        int pos = (int)(((unsigned)info) >> 8) +                         \
                  (g ? __popc(mb & 0xFu) : 0);                           \
        unsigned nib = (mb >> (g * 4)) & 0xFu;                           \
        if (nib & 1u) { out[pos] = OD[0]; pos++; }                       \
        if (nib & 2u) { out[pos] = OD[1]; pos++; }                       \
        if (nib & 4u) { out[pos] = OD[2]; pos++; }                       \
        if (nib & 8u) { out[pos] = OD[3]; }                              }
        EPI(0, O0) EPI(1, O1) EPI(2, O2) EPI(3, O3)
#undef EPI
      }
    } else {
#pragma unroll
      for (int r = 0; r < 4; ++r) {
        keep += O0[r] + O1[r] + O2[r] + O3[r];
        if constexpr (MODE == 3) keep += P0[r] + P1[r] + P2[r] + P3[r];
      }
    }
  }

  if constexpr (MODE != 0) dbg[blockIdx.x * MLP_THREADS + tid] = keep;
}

extern "C" void kernel_launch(void* const* d_in, const int* in_sizes, int n_in,
                              void* d_out, int out_size, void* d_ws, size_t ws_size,
                              hipStream_t stream) {
  const float* x    = (const float*)d_in[0];
  const int*   mask = (const int*)d_in[1];
  const float* w0   = (const float*)d_in[2];
  const float* b0   = (const float*)d_in[3];
  const float* w1   = (const float*)d_in[4];
  const float* b1   = (const float*)d_in[5];
  float* out = (float*)d_out;

  int* bsum    = (int*)d_ws;
  int* boff    = bsum + NB;
  int* rowinfo = boff + NB;
  float* dbg   = (float*)(rowinfo + NROWS);

  count_kernel<<<NB, 256, 0, stream>>>(mask, bsum);
  scan_kernel<<<1, 1024, 0, stream>>>(bsum, boff);
  expand_kernel<<<NB, 256, 0, stream>>>(mask, boff, rowinfo);
  mlp_t<0><<<MLP_BLOCKS, MLP_THREADS, 0, stream>>>(x, w0, b0, w1, b1, rowinfo, out, dbg);
  mlp_t<1><<<MLP_BLOCKS, MLP_THREADS, 0, stream>>>(x, w0, b0, w1, b1, rowinfo, out, dbg);
  mlp_t<2><<<MLP_BLOCKS, MLP_THREADS, 0, stream>>>(x, w0, b0, w1, b1, rowinfo, out, dbg);
  mlp_t<3><<<MLP_BLOCKS, MLP_THREADS, 0, stream>>>(x, w0, b0, w1, b1, rowinfo, out, dbg);
}

// Round 23
// 87.867 us; speedup vs baseline: 2.6074x; 2.6074x over previous
//
#include <hip/hip_runtime.h>

#define NROWS 1000000
#define NB    3907         // ceil(1e6 / 256) mask blocks
#define NT    62500        // 16-row tiles
#define TPB   4            // tiles per wave-batch
#define NBATCH (NT / TPB)  // 15625, exact
#define MLP_BLOCKS 768
#define MLP_THREADS 512

typedef __bf16 bf16x8 __attribute__((ext_vector_type(8)));
typedef float  f32x4  __attribute__((ext_vector_type(4)));

// f32 pair -> packed bf16 (RNE), 1 instr (T12 recipe; verified R10-R19)
__device__ __forceinline__ unsigned cvt_pk_bf16(float lo, float hi) {
  unsigned r;
  asm("v_cvt_pk_bf16_f32 %0, %1, %2" : "=v"(r) : "v"(lo), "v"(hi));
  return r;
}
// NOTE: v_pk_max_i16 relu is BANNED (NaN twice: R9, R18).

// ---------------------------------------------------------------------------
// Kernel 1: per-256-row-block nonzero counts (3907 sums).
// ---------------------------------------------------------------------------
__global__ __launch_bounds__(256) void count_kernel(
    const int* __restrict__ mask, int* __restrict__ bsum) {
  int tid = threadIdx.x;
  int row = blockIdx.x * 256 + tid;
  int cnt = 0;
  if (row < NROWS) {
    const int4* mp = (const int4*)(mask + (long)row * 8);
    int4 a = mp[0], b = mp[1];
    cnt = (a.x != 0) + (a.y != 0) + (a.z != 0) + (a.w != 0) +
          (b.x != 0) + (b.y != 0) + (b.z != 0) + (b.w != 0);
  }
#pragma unroll
  for (int off = 1; off < 64; off <<= 1) cnt += __shfl_xor(cnt, off);
  __shared__ int ws[4];
  if ((tid & 63) == 0) ws[tid >> 6] = cnt;
  __syncthreads();
  if (tid == 0) bsum[blockIdx.x] = ws[0] + ws[1] + ws[2] + ws[3];
}

// ---------------------------------------------------------------------------
// Kernel 2: exclusive scan of 3907 block sums (single block).
// ---------------------------------------------------------------------------
__global__ __launch_bounds__(1024) void scan_kernel(
    const int* __restrict__ bsum, int* __restrict__ boff) {
  __shared__ int lds[1024];
  int t = threadIdx.x;
  int i0 = t * 4;
  int c0 = (i0 + 0 < NB) ? bsum[i0 + 0] : 0;
  int c1 = (i0 + 1 < NB) ? bsum[i0 + 1] : 0;
  int c2 = (i0 + 2 < NB) ? bsum[i0 + 2] : 0;
  int c3 = (i0 + 3 < NB) ? bsum[i0 + 3] : 0;
  int s = c0 + c1 + c2 + c3;
  lds[t] = s;
  __syncthreads();
  for (int off = 1; off < 1024; off <<= 1) {
    int v = lds[t];
    int add = (t >= off) ? lds[t - off] : 0;
    __syncthreads();
    lds[t] = v + add;
    __syncthreads();
  }
  int excl = lds[t] - s;
  if (i0 + 0 < NB) boff[i0 + 0] = excl;
  excl += c0;
  if (i0 + 1 < NB) boff[i0 + 1] = excl;
  excl += c1;
  if (i0 + 2 < NB) boff[i0 + 2] = excl;
  excl += c2;
  if (i0 + 3 < NB) boff[i0 + 3] = excl;
}

// ---------------------------------------------------------------------------
// Kernel 3: per-row info = (scatter_pos << 8) | mask_bits.
// ---------------------------------------------------------------------------
__global__ __launch_bounds__(256) void expand_kernel(
    const int* __restrict__ mask, const int* __restrict__ boff,
    int* __restrict__ rowinfo) {
  int tid = threadIdx.x;
  int row = blockIdx.x * 256 + tid;
  bool valid = row < NROWS;
  unsigned mb = 0;
  int cnt = 0;
  if (valid) {
    const int4* mp = (const int4*)(mask + (long)row * 8);
    int4 a = mp[0], b = mp[1];
    mb = (unsigned)((a.x != 0) | ((a.y != 0) << 1) | ((a.z != 0) << 2) |
                    ((a.w != 0) << 3) | ((b.x != 0) << 4) | ((b.y != 0) << 5) |
                    ((b.z != 0) << 6) | ((b.w != 0) << 7));
    cnt = __popc(mb);
  }
  int incl = cnt;
#pragma unroll
  for (int off = 1; off < 64; off <<= 1) {
    int v = __shfl_up(incl, off);
    if ((tid & 63) >= off) incl += v;
  }
  __shared__ int wsum[4];
  if ((tid & 63) == 63) wsum[tid >> 6] = incl;
  __syncthreads();
  int w = tid >> 6;
  int wo = 0;
  if (w > 0) wo += wsum[0];
  if (w > 1) wo += wsum[1];
  if (w > 2) wo += wsum[2];
  int pos = boff[blockIdx.x] + wo + (incl - cnt);
  if (valid) rowinfo[row] = (pos << 8) | (int)mb;
}

// ---------------------------------------------------------------------------
// Kernel 4: R19 kernel with ONE change: head loop unroll 1 -> 2.
// R22 ablation: M1 (reg operands, cvt kept) = 86us; M2 (cvt removed) ~ 30us.
// The binder is the exposed D->fmax->cvt->L1 dependency, and unroll 1 was
// forbidding cross-head software pipelining. Unroll 2 lets the scheduler
// issue head cp+1's L0 MFMAs under head cp's cvt chain.
// ---------------------------------------------------------------------------
__global__ __launch_bounds__(MLP_THREADS, 4) void mlp_kernel(
    const float* __restrict__ x, const float* __restrict__ w0,
    const float* __restrict__ b0, const float* __restrict__ w1,
    const float* __restrict__ b1, const int* __restrict__ rowinfo,
    float* __restrict__ out) {
  __shared__ __bf16 sA[32 * 64 * 8];   // 32 frags x 64 lanes x 8 bf16 = 32 KB
  __shared__ float sB0[512];

  int tid = threadIdx.x;
#pragma unroll
  for (int i = 0; i < 4; ++i) {
    int fi = i * MLP_THREADS + tid;
    int frag = fi >> 6;
    int lane = fi & 63;
    int d = frag >> 2, qb = frag & 3;
    int q = qb * 16 + (lane & 15);
    int kb = (lane >> 4) * 8;
    bf16x8 v;
#pragma unroll
    for (int j = 0; j < 8; ++j)
      v[j] = (__bf16)w0[d * 2048 + (kb + j) * 64 + q];
    *(bf16x8*)&sA[fi * 8] = v;
  }
  if (tid < 128) *(float4*)&sB0[tid * 4] = *(const float4*)&b0[tid * 4];
  __syncthreads();

  int l = tid & 63;
  int n = l & 15;
  int g = l >> 4;

  bf16x8 w1A, w1B;
  bool ownrow = (n < 8);
#pragma unroll
  for (int j = 0; j < 8; ++j) {
    int off = (j >> 2) * 16 + g * 4 + (j & 3);
    w1A[j] = ownrow ? (__bf16)w1[n * 64 + off]      : (__bf16)0.f;
    w1B[j] = ownrow ? (__bf16)w1[n * 64 + 32 + off] : (__bf16)0.f;
  }
  int4 w1Ai = *(int4*)&w1A;
  int4 w1Bi = *(int4*)&w1B;
  f32x4 b1C;
#pragma unroll
  for (int r = 0; r < 4; ++r) b1C[r] = b1[(g * 4 + r) & 7];

  int w = tid >> 6;                    // wave 0..7
  int wv = blockIdx.x * 8 + w;
  const int W = MLP_BLOCKS * 8;        // 6144 waves

  for (int b = wv; b < NBATCH; b += W) {
    int t0 = b * TPB;

    bf16x8 xf0, xf1, xf2, xf3;
    {
      const float* xp;
      float4 a, c;
      uint4 ui;
#define LOADX(T, DST)                                              \
      xp = x + (long)((t0 + T) * 16 + n) * 32 + g * 8;             \
      a = *(const float4*)xp; c = *(const float4*)(xp + 4);        \
      ui.x = cvt_pk_bf16(a.x, a.y); ui.y = cvt_pk_bf16(a.z, a.w); \
      ui.z = cvt_pk_bf16(c.x, c.y); ui.w = cvt_pk_bf16(c.z, c.w); \
      DST = *(bf16x8*)&ui;
      LOADX(0, xf0) LOADX(1, xf1) LOADX(2, xf2) LOADX(3, xf3)
#undef LOADX
    }

    f32x4 O0 = b1C, O1 = b1C, O2 = b1C, O3 = b1C;

#pragma unroll 2
    for (int cp = 0; cp < 8; ++cp) {
      bool own = (n == cp);
      int4 z4 = {0, 0, 0, 0};
      int4 A2ai = own ? w1Ai : z4;
      int4 A2bi = own ? w1Bi : z4;
      bf16x8 A2a = *(bf16x8*)&A2ai;
      bf16x8 A2b = *(bf16x8*)&A2bi;
      int fb2 = cp * 4;
      bf16x8 Aw0 = *(const bf16x8*)&sA[(fb2 + 0) * 512 + l * 8];
      bf16x8 Aw1 = *(const bf16x8*)&sA[(fb2 + 1) * 512 + l * 8];
      bf16x8 Aw2 = *(const bf16x8*)&sA[(fb2 + 2) * 512 + l * 8];
      bf16x8 Aw3 = *(const bf16x8*)&sA[(fb2 + 3) * 512 + l * 8];
      f32x4 C0 = *(const f32x4*)&sB0[(fb2 + 0) * 16 + g * 4];
      f32x4 C1 = *(const f32x4*)&sB0[(fb2 + 1) * 16 + g * 4];
      f32x4 C2 = *(const f32x4*)&sB0[(fb2 + 2) * 16 + g * 4];
      f32x4 C3 = *(const f32x4*)&sB0[(fb2 + 3) * 16 + g * 4];

#define TILE2(XFa, OA, XFb, OB) {                                             \
      f32x4 Da0 = __builtin_amdgcn_mfma_f32_16x16x32_bf16(Aw0, XFa, C0,0,0,0);\
      f32x4 Db0 = __builtin_amdgcn_mfma_f32_16x16x32_bf16(Aw0, XFb, C0,0,0,0);\
      f32x4 Da1 = __builtin_amdgcn_mfma_f32_16x16x32_bf16(Aw1, XFa, C1,0,0,0);\
      f32x4 Db1 = __builtin_amdgcn_mfma_f32_16x16x32_bf16(Aw1, XFb, C1,0,0,0);\
      uint4 ua, ub;                                                           \
      ua.x = cvt_pk_bf16(fmaxf(Da0[0], 0.f), fmaxf(Da0[1], 0.f));             \
      ua.y = cvt_pk_bf16(fmaxf(Da0[2], 0.f), fmaxf(Da0[3], 0.f));             \
      ub.x = cvt_pk_bf16(fmaxf(Db0[0], 0.f), fmaxf(Db0[1], 0.f));             \
      ub.y = cvt_pk_bf16(fmaxf(Db0[2], 0.f), fmaxf(Db0[3], 0.f));             \
      ua.z = cvt_pk_bf16(fmaxf(Da1[0], 0.f), fmaxf(Da1[1], 0.f));             \
      ua.w = cvt_pk_bf16(fmaxf(Da1[2], 0.f), fmaxf(Da1[3], 0.f));             \
      ub.z = cvt_pk_bf16(fmaxf(Db1[0], 0.f), fmaxf(Db1[1], 0.f));             \
      ub.w = cvt_pk_bf16(fmaxf(Db1[2], 0.f), fmaxf(Db1[3], 0.f));             \
      bf16x8 B2a = *(bf16x8*)&ua;                                             \
      bf16x8 B2b = *(bf16x8*)&ub;                                             \
      OA = __builtin_amdgcn_mfma_f32_16x16x32_bf16(A2a, B2a, OA, 0, 0, 0);    \
      OB = __builtin_amdgcn_mfma_f32_16x16x32_bf16(A2a, B2b, OB, 0, 0, 0);    \
      f32x4 Da2 = __builtin_amdgcn_mfma_f32_16x16x32_bf16(Aw2, XFa, C2,0,0,0);\
      f32x4 Db2 = __builtin_amdgcn_mfma_f32_16x16x32_bf16(Aw2, XFb, C2,0,0,0);\
      f32x4 Da3 = __builtin_amdgcn_mfma_f32_16x16x32_bf16(Aw3, XFa, C3,0,0,0);\
      f32x4 Db3 = __builtin_amdgcn_mfma_f32_16x16x32_bf16(Aw3, XFb, C3,0,0,0);\
      ua.x = cvt_pk_bf16(fmaxf(Da2[0], 0.f), fmaxf(Da2[1], 0.f));             \
      ua.y = cvt_pk_bf16(fmaxf(Da2[2], 0.f), fmaxf(Da2[3], 0.f));             \
      ub.x = cvt_pk_bf16(fmaxf(Db2[0], 0.f), fmaxf(Db2[1], 0.f));             \
      ub.y = cvt_pk_bf16(fmaxf(Db2[2], 0.f), fmaxf(Db2[3], 0.f));             \
      ua.z = cvt_pk_bf16(fmaxf(Da3[0], 0.f), fmaxf(Da3[1], 0.f));             \
      ua.w = cvt_pk_bf16(fmaxf(Da3[2], 0.f), fmaxf(Da3[3], 0.f));             \
      ub.z = cvt_pk_bf16(fmaxf(Db3[0], 0.f), fmaxf(Db3[1], 0.f));             \
      ub.w = cvt_pk_bf16(fmaxf(Db3[2], 0.f), fmaxf(Db3[3], 0.f));             \
      bf16x8 B3a = *(bf16x8*)&ua;                                             \
      bf16x8 B3b = *(bf16x8*)&ub;                                             \
      OA = __builtin_amdgcn_mfma_f32_16x16x32_bf16(A2b, B3a, OA, 0, 0, 0);    \
      OB = __builtin_amdgcn_mfma_f32_16x16x32_bf16(A2b, B3b, OB, 0, 0, 0); }
      TILE2(xf0, O0, xf1, O1)
      TILE2(xf2, O2, xf3, O3)
#undef TILE2
    }

    // ---- epilogue: lanes g<2 hold out[d=g*4+r][n]; ordered scatter ----
    if (g < 2) {
#define EPI(T, OD) {                                                     \
      int row = (t0 + T) * 16 + n;                                       \
      int info = rowinfo[row];                                           \
      unsigned mb = (unsigned)info & 255u;                               \
      int pos = (int)(((unsigned)info) >> 8) +                           \
                (g ? __popc(mb & 0xFu) : 0);                             \
      unsigned nib = (mb >> (g * 4)) & 0xFu;                             \
      if (nib & 1u) { out[pos] = OD[0]; pos++; }                         \
      if (nib & 2u) { out[pos] = OD[1]; pos++; }                         \
      if (nib & 4u) { out[pos] = OD[2]; pos++; }                         \
      if (nib & 8u) { out[pos] = OD[3]; }                                }
      EPI(0, O0) EPI(1, O1) EPI(2, O2) EPI(3, O3)
#undef EPI
    }
  }
}

extern "C" void kernel_launch(void* const* d_in, const int* in_sizes, int n_in,
                              void* d_out, int out_size, void* d_ws, size_t ws_size,
                              hipStream_t stream) {
  const float* x    = (const float*)d_in[0];
  const int*   mask = (const int*)d_in[1];
  const float* w0   = (const float*)d_in[2];
  const float* b0   = (const float*)d_in[3];
  const float* w1   = (const float*)d_in[4];
  const float* b1   = (const float*)d_in[5];
  float* out = (float*)d_out;

  int* bsum    = (int*)d_ws;
  int* boff    = bsum + NB;
  int* rowinfo = boff + NB;

  count_kernel<<<NB, 256, 0, stream>>>(mask, bsum);
  scan_kernel<<<1, 1024, 0, stream>>>(bsum, boff);
  expand_kernel<<<NB, 256, 0, stream>>>(mask, boff, rowinfo);
  mlp_kernel<<<MLP_BLOCKS, MLP_THREADS, 0, stream>>>(x, w0, b0, w1, b1, rowinfo, out);
}